// Round 2
// baseline (364.836 us; speedup 1.0000x reference)
//
#include <hip/hip_runtime.h>

typedef unsigned short ushort;
typedef __bf16 bf16x8 __attribute__((ext_vector_type(8)));
typedef float f32x4 __attribute__((ext_vector_type(4)));

#define F_IN 256
#define CCH  128
#define BSH  7
#define BNODES 128
#define NBUCK 1024
#define CHUNK 2048

// ---------------- helpers ----------------
__device__ __forceinline__ ushort f2bf(float f) {
    union { float f; unsigned i; } u; u.f = f;
    unsigned r = u.i + 0x7fffu + ((u.i >> 16) & 1u);   // RNE
    return (ushort)(r >> 16);
}
__device__ __forceinline__ float2 bf2f2(unsigned u) {
    union { unsigned i; float f; } lo, hi;
    lo.i = u << 16;
    hi.i = u & 0xffff0000u;
    return make_float2(lo.f, hi.f);
}
__device__ __forceinline__ void gload_lds16(const void* g, void* l) {
    __builtin_amdgcn_global_load_lds((const __attribute__((address_space(1))) unsigned*)g,
                                     (__attribute__((address_space(3))) unsigned*)l, 16, 0, 0);
}

// ---------------- K1: per-chunk histogram (dual layout) + weight cvt ----------------
// w1b is written PRE-SWIZZLED: within each 32-col k-tile, 8-elem chunk c -> c ^ ((row>>1)&3).
// gemm stages it with linear global_load_lds and applies the same XOR on the ds_read side
// (both-sides-or-neither rule; the source permutation IS the read permutation).
__global__ __launch_bounds__(256)
void hist_cvt(const int* __restrict__ dst, int* __restrict__ histC, int* __restrict__ histT,
              int E, int nchunks, int ncp,
              const float* __restrict__ W1, const float* __restrict__ W2,
              ushort* __restrict__ w1b, ushort* __restrict__ w2b)
{
    const int blk = blockIdx.x, t = threadIdx.x;
    if (blk >= nchunks) {
        int i = (blk - nchunks) * 256 + t;
        if (i < CCH * F_IN) {
            int c  = i & 31;
            int cs = c ^ (((i >> 9) & 3) << 3);        // (row>>1)&3, row = i>>8
            w1b[(i & ~31) | cs] = f2bf(W1[i]);
        } else {
            int j = i - CCH * F_IN;
            if (j < CCH * CCH) w2b[j] = f2bf(W2[j]);
        }
        return;
    }
    __shared__ int h[NBUCK];
    for (int i = t; i < NBUCK; i += 256) h[i] = 0;
    __syncthreads();
    int cb = blk * CHUNK, ce = min(cb + CHUNK, E);
    for (int e = cb + t; e < ce; e += 256)
        atomicAdd(&h[dst[e] >> BSH], 1);
    __syncthreads();
    for (int i = t; i < NBUCK; i += 256) {
        int v = h[i];
        histC[blk * NBUCK + i] = v;     // chunk-major (partition)
        histT[i * ncp + blk]   = v;     // bucket-major (scan)
    }
}

// ---------------- K2: per-bucket cross-chunk prefix (one wave per bucket) ----------------
__global__ __launch_bounds__(256)
void scan_buckets(const int* __restrict__ histT, int* __restrict__ prefT,
                  int* __restrict__ btot, int nchunks, int ncp)
{
    const int b = blockIdx.x * 4 + (threadIdx.x >> 6);
    const int lane = threadIdx.x & 63;
    int carry = 0;
    for (int c = 0; c < nchunks; c += 64) {
        int idx = c + lane;
        int v = (idx < nchunks) ? histT[b * ncp + idx] : 0;
        int inc = v;
#pragma unroll
        for (int off = 1; off < 64; off <<= 1) {
            int x = __shfl_up(inc, off, 64);
            if (lane >= off) inc += x;
        }
        if (idx < nchunks) prefT[b * ncp + idx] = carry + inc - v;
        carry += __shfl(inc, 63, 64);
    }
    if (lane == 0) btot[b] = carry;
}

// ---------------- K3: partition (deterministic slots, no global atomics) ----------------
__global__ __launch_bounds__(256)
void partition_kernel(const int* __restrict__ src, const int* __restrict__ dst,
                      const int* __restrict__ histC, const int* __restrict__ prefT,
                      const int* __restrict__ btot, int* __restrict__ gbase,
                      unsigned* __restrict__ pairs, int E, int ncp)
{
    __shared__ int lbase[NBUCK];
    __shared__ int lcur[NBUCK];
    __shared__ int rb2[NBUCK];
    __shared__ int base_s[NBUCK];
    __shared__ int ssum[256];
    __shared__ unsigned sp[CHUNK];   // 8 KB
    __shared__ ushort  sb[CHUNK];    // 4 KB
    const int t = threadIdx.x, blk = blockIdx.x;

    // scan this chunk's hist -> lbase/lcur
    int4 cv = *(const int4*)&histC[blk * NBUCK + 4 * t];
    int tsum = cv.x + cv.y + cv.z + cv.w;
    ssum[t] = tsum;
    __syncthreads();
    for (int off = 1; off < 256; off <<= 1) {
        int x = (t >= off) ? ssum[t - off] : 0;
        __syncthreads();
        ssum[t] += x;
        __syncthreads();
    }
    int texcl = ssum[t] - tsum;
    lbase[4 * t]     = texcl;
    lbase[4 * t + 1] = texcl + cv.x;
    lbase[4 * t + 2] = texcl + cv.x + cv.y;
    lbase[4 * t + 3] = texcl + cv.x + cv.y + cv.z;
    lcur[4 * t]     = lbase[4 * t];
    lcur[4 * t + 1] = lbase[4 * t + 1];
    lcur[4 * t + 2] = lbase[4 * t + 2];
    lcur[4 * t + 3] = lbase[4 * t + 3];
    __syncthreads();

    // scan bucket totals -> base_s
    int4 bt = *(const int4*)&btot[4 * t];
    int bsum = bt.x + bt.y + bt.z + bt.w;
    ssum[t] = bsum;
    __syncthreads();
    for (int off = 1; off < 256; off <<= 1) {
        int x = (t >= off) ? ssum[t - off] : 0;
        __syncthreads();
        ssum[t] += x;
        __syncthreads();
    }
    int bexcl = ssum[t] - bsum;
    base_s[4 * t]     = bexcl;
    base_s[4 * t + 1] = bexcl + bt.x;
    base_s[4 * t + 2] = bexcl + bt.x + bt.y;
    base_s[4 * t + 3] = bexcl + bt.x + bt.y + bt.z;
    if (blk == 0) {
        *(int4*)&gbase[4 * t] = *(int4*)&base_s[4 * t];
        if (t == 255) gbase[NBUCK] = ssum[255];
    }
    __syncthreads();
    for (int i = t; i < NBUCK; i += 256)
        rb2[i] = base_s[i] + prefT[i * ncp + blk];
    __syncthreads();

    const int cb = blk * CHUNK, ce = min(cb + CHUNK, E);
    for (int e = cb + t; e < ce; e += 256) {
        int d = dst[e];
        int b = d >> BSH;
        unsigned packed = ((unsigned)src[e] << BSH) | (unsigned)(d & (BNODES - 1));
        int p = atomicAdd(&lcur[b], 1);
        sp[p] = packed;
        sb[p] = (ushort)b;
    }
    __syncthreads();
    const int cnt = ce - cb;
    for (int i = t; i < cnt; i += 256) {
        int b = sb[i];
        pairs[rb2[b] + (i - lbase[b])] = sp[i];
    }
}

// ---------------- K4: per-bucket CSR finalize ----------------
__global__ __launch_bounds__(256)
void bucket_csr(const unsigned* __restrict__ pairs, const int* __restrict__ base,
                int* __restrict__ row_start, float* __restrict__ dinv,
                unsigned* __restrict__ csr, int N, int E)
{
    __shared__ int deg[BNODES];
    __shared__ int s[BNODES];
    __shared__ int cur[BNODES];
    const int b = blockIdx.x, t = threadIdx.x;
    if (t < BNODES) deg[t] = 0;
    __syncthreads();
    const int rb = base[b], re = base[b + 1];
    for (int e = rb + t; e < re; e += 256)
        atomicAdd(&deg[pairs[e] & (BNODES - 1)], 1);
    __syncthreads();
    int v = (t < BNODES) ? deg[t] : 0;
    if (t < BNODES) s[t] = v;
    __syncthreads();
    for (int off = 1; off < BNODES; off <<= 1) {
        int x = (t >= off && t < BNODES) ? s[t - off] : 0;
        __syncthreads();
        if (t < BNODES) s[t] += x;
        __syncthreads();
    }
    const int n0 = b << BSH;
    if (t < BNODES) {
        int excl = s[t] - v;
        cur[t] = excl;
        if (n0 + t < N) {
            row_start[n0 + t] = rb + excl;
            dinv[n0 + t] = rsqrtf((float)v + 1.0f);
        }
    }
    if (b == gridDim.x - 1 && t == 0) row_start[N] = E;
    __syncthreads();
    for (int e = rb + t; e < re; e += 256) {
        unsigned p = pairs[e];
        int l = p & (BNODES - 1);
        int slot = atomicAdd(&cur[l], 1);
        csr[rb + slot] = p >> BSH;
    }
}

// ---------------- K5: fused pipelined GEMM: z' = (relu(x@W1^T+b1) @ W2^T) * dinv ----------------
//  * LDS = 32768 B declared: A0|B0|A1|B1 k-tiles (4 x [128][32] bf16 = 4x8KB, double-buffered),
//    fully aliased by unpadded swizzled Ht[128][128].  -> 4 blocks/CU (was 53248 B -> 3).
//  * B (W1, already bf16) staged with global_load_lds dwordx4 (no VGPR round-trip, no ds_write).
//    Bank-conflict-reduced via PRE-SWIZZLED w1b in global (chunk c ^= (row>>1)&3 per 32-col tile);
//    LDS stays linear (global_load_lds constraint), ds_read applies the same XOR.
//  * A (f32->bf16 cvt needed) reg-staged with the same chunk XOR applied at ds_write.
//  * Ht: pad removed (stride 128), byte-XOR swizzle ((row&7)<<4) => conflict-free b128 frag reads.
//  * Phase B: NO LDS staging, NO barriers in the k-loop — W2 frags straight from global (L2-hot),
//    double-prefetched in regs; issued before epilogue A to hide latency.
//  * Barriers 19 -> 12.  __launch_bounds__(256,4) caps VGPR at 128 for 16 waves/CU.
__global__ __launch_bounds__(256, 4)
void gemm_fused(const float* __restrict__ X, const ushort* __restrict__ W1b,
                const ushort* __restrict__ W2b, const float* __restrict__ b1,
                const float* __restrict__ dinv, ushort* __restrict__ Zq, int M)
{
    __shared__ ushort smem[16384];          // 32768 B
    ushort* Ht = smem;                      // [128][128] bf16, swizzled, aliases all 4 k-tile bufs
    const int tid  = threadIdx.x;
    const int wave = tid >> 6, lane = tid & 63;
    const int wm = (wave & 1) * 64, wn = (wave >> 1) * 64;
    const int lr = lane & 15, lq = lane >> 4;
    const int m0 = blockIdx.x * 128;

    const int arow = tid >> 2;              // staging row (+64 for second)
    const int aq   = tid & 3;               // 16B chunk within the 64B k-slice

    float4 ar[2][2];
    auto loadX = [&](int k0) {
#pragma unroll
        for (int it = 0; it < 2; it++) {
            int row = arow + it * 64;
            ar[it][0] = make_float4(0.f, 0.f, 0.f, 0.f);
            ar[it][1] = make_float4(0.f, 0.f, 0.f, 0.f);
            if (m0 + row < M) {
                const float* p = &X[(long)(m0 + row) * F_IN + k0 + aq * 8];
                ar[it][0] = *(const float4*)p;
                ar[it][1] = *(const float4*)(p + 4);
            }
        }
    };
    auto writeA = [&](ushort* As) {
#pragma unroll
        for (int it = 0; it < 2; it++) {
            int row = arow + it * 64;
            ushort u[8] = { f2bf(ar[it][0].x), f2bf(ar[it][0].y), f2bf(ar[it][0].z), f2bf(ar[it][0].w),
                            f2bf(ar[it][1].x), f2bf(ar[it][1].y), f2bf(ar[it][1].z), f2bf(ar[it][1].w) };
            *(uint4*)&As[row * 32 + ((aq ^ ((row >> 1) & 3)) << 3)] = *(uint4*)u;
        }
    };
    auto stageB = [&](int k0, ushort* Bs) {
#pragma unroll
        for (int it = 0; it < 2; it++) {
            int r0 = wave * 32 + it * 16;                        // wave-uniform LDS dest
            const ushort* g = &W1b[(long)(r0 + (lane >> 2)) * F_IN + k0 + (lane & 3) * 8];
            gload_lds16(g, &Bs[r0 * 32]);
        }
    };

    // ---- phase A: acc = x @ W1^T (K=256) ----
    f32x4 acc[4][4] = {};
    loadX(0);
    stageB(0, smem + 4096);
    writeA(smem);
    __syncthreads();
    for (int k0 = 0; k0 < F_IN; k0 += 32) {
        const int cur = (k0 >> 5) & 1;
        ushort* As = smem + cur * 8192;
        ushort* Bs = As + 4096;
        const bool more = (k0 + 32 < F_IN);
        if (more) {
            stageB(k0 + 32, smem + (cur ^ 1) * 8192 + 4096);    // async DMA into alt buf
            loadX(k0 + 32);                                     // reg prefetch
        }
        bf16x8 af[4], bfr[4];
#pragma unroll
        for (int t4 = 0; t4 < 4; t4++) {
            int ra = wm + t4 * 16 + lr;
            int rb = wn + t4 * 16 + lr;
            af[t4]  = *(bf16x8*)&As[ra * 32 + ((lq ^ ((ra >> 1) & 3)) << 3)];
            bfr[t4] = *(bf16x8*)&Bs[rb * 32 + ((lq ^ ((rb >> 1) & 3)) << 3)];
        }
#pragma unroll
        for (int i = 0; i < 4; i++)
#pragma unroll
            for (int j = 0; j < 4; j++)
                acc[i][j] = __builtin_amdgcn_mfma_f32_16x16x32_bf16(af[i], bfr[j], acc[i][j], 0, 0, 0);
        if (more) writeA(smem + (cur ^ 1) * 8192);              // cvt+ds_write into alt buf
        __syncthreads();
    }

    // prefetch W2 frags for k0=0 (latency hidden under epilogue A)
    uint4 wb[2][4];
#pragma unroll
    for (int t4 = 0; t4 < 4; t4++)
        wb[0][t4] = *(const uint4*)&W2b[(long)(wn + t4 * 16 + lr) * CCH + lq * 8];

    // ---- epilogue A: h = relu(acc + b1) -> Ht (swizzled) ----
    {
        float bv[4];
#pragma unroll
        for (int j = 0; j < 4; j++) bv[j] = b1[wn + j * 16 + lr];
#pragma unroll
        for (int i = 0; i < 4; i++)
#pragma unroll
            for (int r = 0; r < 4; r++) {
                int row = wm + i * 16 + lq * 4 + r;
                int rx  = (row & 7) << 3;
#pragma unroll
                for (int j = 0; j < 4; j++)
                    Ht[row * 128 + ((wn + j * 16 + lr) ^ rx)] = f2bf(fmaxf(acc[i][j][r] + bv[j], 0.f));
            }
    }
    __syncthreads();

    // ---- phase B: acc2 = h @ W2^T (K=128), barrier-free: A from Ht, B direct from global ----
    f32x4 acc2[4][4] = {};
#pragma unroll
    for (int kk = 0; kk < 4; kk++) {
        const int k0 = kk * 32;
        if (kk < 3) {
#pragma unroll
            for (int t4 = 0; t4 < 4; t4++)
                wb[(kk + 1) & 1][t4] =
                    *(const uint4*)&W2b[(long)(wn + t4 * 16 + lr) * CCH + k0 + 32 + lq * 8];
        }
        bf16x8 af[4];
#pragma unroll
        for (int t4 = 0; t4 < 4; t4++) {
            int ra = wm + t4 * 16 + lr;
            af[t4] = *(bf16x8*)&Ht[ra * 128 + ((k0 + lq * 8) ^ ((ra & 7) << 3))];
        }
#pragma unroll
        for (int i = 0; i < 4; i++)
#pragma unroll
            for (int j = 0; j < 4; j++)
                acc2[i][j] = __builtin_amdgcn_mfma_f32_16x16x32_bf16(af[i], *(bf16x8*)&wb[kk & 1][j],
                                                                     acc2[i][j], 0, 0, 0);
    }
    __syncthreads();   // all Ht frag reads done before overwrite

    // ---- epilogue B: z' = acc2 * dinv -> Ht (swizzled) -> coalesced store ----
#pragma unroll
    for (int i = 0; i < 4; i++)
#pragma unroll
        for (int r = 0; r < 4; r++) {
            int row = wm + i * 16 + lq * 4 + r;
            int rx  = (row & 7) << 3;
            float di = (m0 + row < M) ? dinv[m0 + row] : 0.f;
#pragma unroll
            for (int j = 0; j < 4; j++)
                Ht[row * 128 + ((wn + j * 16 + lr) ^ rx)] = f2bf(acc2[i][j][r] * di);
        }
    __syncthreads();
    {
        int colq = tid & 15, row0 = tid >> 4;
#pragma unroll
        for (int i = 0; i < 8; i++) {
            int row = row0 + i * 16;
            if (m0 + row < M)
                *(uint4*)&Zq[(long)(m0 + row) * CCH + colq * 8] =
                    *(uint4*)&Ht[row * 128 + ((colq * 8) ^ ((row & 7) << 3))];
        }
    }
}

// ---------------- K6: gather ----------------
__global__ __launch_bounds__(256)
void gather_nodes(const unsigned* __restrict__ zq, const unsigned* __restrict__ csr,
                  const int* __restrict__ row_start, const float* __restrict__ dinv,
                  const float* __restrict__ b2, float* __restrict__ out, int N)
{
    const int node = blockIdx.x * 4 + (threadIdx.x >> 6);
    const int lane = threadIdx.x & 63;
    if (node >= N) return;

    float2 zs = bf2f2(zq[(long)node * 64 + lane]);
    float acc0 = zs.x, acc1 = zs.y;

    const int rs = row_start[node];
    const int re = row_start[node + 1];
    int j = rs;
    for (; j + 8 <= re; j += 8) {
        unsigned sI[8], zv[8];
#pragma unroll
        for (int q = 0; q < 8; q++) sI[q] = csr[j + q];
#pragma unroll
        for (int q = 0; q < 8; q++) zv[q] = zq[(long)sI[q] * 64 + lane];
#pragma unroll
        for (int q = 0; q < 8; q++) { float2 f = bf2f2(zv[q]); acc0 += f.x; acc1 += f.y; }
    }
    for (; j < re; j++) {
        float2 f = bf2f2(zq[(long)csr[j] * 64 + lane]);
        acc0 += f.x; acc1 += f.y;
    }

    float di = dinv[node];
    float2 o;
    o.x = b2[lane * 2 + 0] + di * acc0;
    o.y = b2[lane * 2 + 1] + di * acc1;
    *(float2*)&out[(long)node * CCH + lane * 2] = o;
}

extern "C" void kernel_launch(void* const* d_in, const int* in_sizes, int n_in,
                              void* d_out, int out_size, void* d_ws, size_t ws_size,
                              hipStream_t stream)
{
    const float* x  = (const float*)d_in[0];
    const int*   ei = (const int*)d_in[1];
    const float* W1 = (const float*)d_in[2];
    const float* b1 = (const float*)d_in[3];
    const float* W2 = (const float*)d_in[4];
    const float* b2 = (const float*)d_in[5];
    float* out = (float*)d_out;

    const int N = in_sizes[0] / F_IN;
    const int E = in_sizes[1] / 2;
    const int* src = ei;
    const int* dst = ei + E;

    const int nchunks = (E + CHUNK - 1) / CHUNK;        // 782
    const int ncp     = (nchunks + 63) & ~63;           // 832
    const int nbuck   = (N + BNODES - 1) / BNODES;      // 782
    const int ngrid   = (N + 127) / 128;
    const int ncvt    = (CCH * F_IN + CCH * CCH + 255) / 256;

    char* ws = (char*)d_ws;
    ushort* zq    = (ushort*)ws;   ws += (size_t)N * CCH * 2;
    ushort* w1b   = (ushort*)ws;   ws += (size_t)CCH * F_IN * 2;
    ushort* w2b   = (ushort*)ws;   ws += (size_t)CCH * CCH * 2;
    unsigned* prs = (unsigned*)ws; ws += (size_t)E * 4;
    unsigned* csr = (unsigned*)ws; ws += (size_t)E * 4;
    int* rstart   = (int*)ws;      ws += ((size_t)N + 1) * 4;
    float* dinv   = (float*)ws;    ws += (size_t)N * 4;
    int* histC    = (int*)ws;      ws += (size_t)nchunks * NBUCK * 4;
    int* histT    = (int*)ws;      ws += (size_t)NBUCK * ncp * 4;
    int* prefT    = (int*)ws;      ws += (size_t)NBUCK * ncp * 4;
    int* btot     = (int*)ws;      ws += NBUCK * 4;
    int* gbase    = (int*)ws;      ws += (NBUCK + 1) * 4;

    // build
    hist_cvt<<<nchunks + ncvt, 256, 0, stream>>>(dst, histC, histT, E, nchunks, ncp, W1, W2, w1b, w2b);
    scan_buckets<<<NBUCK / 4, 256, 0, stream>>>(histT, prefT, btot, nchunks, ncp);
    partition_kernel<<<nchunks, 256, 0, stream>>>(src, dst, histC, prefT, btot, gbase, prs, E, ncp);
    bucket_csr<<<nbuck, 256, 0, stream>>>(prs, gbase, rstart, dinv, csr, N, E);

    // fused GEMMs: z' = (relu(x@W1^T + b1) @ W2^T) * dinv   [bf16]
    gemm_fused<<<ngrid, 256, 0, stream>>>(x, w1b, w2b, b1, dinv, zq, N);

    // aggregate
    gather_nodes<<<(N + 3) / 4, 256, 0, stream>>>((const unsigned*)zq, csr, rstart, dinv, b2, out, N);
}

// Round 3
// 323.070 us; speedup vs baseline: 1.1293x; 1.1293x over previous
//
#include <hip/hip_runtime.h>

typedef unsigned short ushort;
typedef __bf16 bf16x8 __attribute__((ext_vector_type(8)));
typedef float f32x4 __attribute__((ext_vector_type(4)));

#define F_IN 256
#define CCH  128
#define BSH  7
#define BNODES 128
#define NBUCK 1024
#define CHUNK 2048

// ---------------- helpers ----------------
__device__ __forceinline__ ushort f2bf(float f) {
    union { float f; unsigned i; } u; u.f = f;
    unsigned r = u.i + 0x7fffu + ((u.i >> 16) & 1u);   // RNE
    return (ushort)(r >> 16);
}
__device__ __forceinline__ float2 bf2f2(unsigned u) {
    union { unsigned i; float f; } lo, hi;
    lo.i = u << 16;
    hi.i = u & 0xffff0000u;
    return make_float2(lo.f, hi.f);
}
__device__ __forceinline__ void gload_lds16(const void* g, void* l) {
    __builtin_amdgcn_global_load_lds((const __attribute__((address_space(1))) unsigned*)g,
                                     (__attribute__((address_space(3))) unsigned*)l, 16, 0, 0);
}

// ---------------- K1: per-chunk histogram (dual layout) + weight cvt ----------------
// w1b is written PRE-SWIZZLED: within each 32-col k-tile, 8-elem chunk c -> c ^ ((row>>1)&3).
// gemm stages it with linear global_load_lds and applies the same XOR on the ds_read side.
__global__ __launch_bounds__(256)
void hist_cvt(const int* __restrict__ dst, int* __restrict__ histC, int* __restrict__ histT,
              int E, int nchunks, int ncp,
              const float* __restrict__ W1, const float* __restrict__ W2,
              ushort* __restrict__ w1b, ushort* __restrict__ w2b)
{
    const int blk = blockIdx.x, t = threadIdx.x;
    if (blk >= nchunks) {
        int i = (blk - nchunks) * 256 + t;
        if (i < CCH * F_IN) {
            int c  = i & 31;
            int cs = c ^ (((i >> 9) & 3) << 3);        // (row>>1)&3, row = i>>8
            w1b[(i & ~31) | cs] = f2bf(W1[i]);
        } else {
            int j = i - CCH * F_IN;
            if (j < CCH * CCH) w2b[j] = f2bf(W2[j]);
        }
        return;
    }
    __shared__ int h[NBUCK];
    for (int i = t; i < NBUCK; i += 256) h[i] = 0;
    __syncthreads();
    int cb = blk * CHUNK, ce = min(cb + CHUNK, E);
    for (int e = cb + t; e < ce; e += 256)
        atomicAdd(&h[dst[e] >> BSH], 1);
    __syncthreads();
    for (int i = t; i < NBUCK; i += 256) {
        int v = h[i];
        histC[blk * NBUCK + i] = v;     // chunk-major (partition)
        histT[i * ncp + blk]   = v;     // bucket-major (scan)
    }
}

// ---------------- K2: per-bucket cross-chunk prefix (one wave per bucket) ----------------
__global__ __launch_bounds__(256)
void scan_buckets(const int* __restrict__ histT, int* __restrict__ prefT,
                  int* __restrict__ btot, int nchunks, int ncp)
{
    const int b = blockIdx.x * 4 + (threadIdx.x >> 6);
    const int lane = threadIdx.x & 63;
    int carry = 0;
    for (int c = 0; c < nchunks; c += 64) {
        int idx = c + lane;
        int v = (idx < nchunks) ? histT[b * ncp + idx] : 0;
        int inc = v;
#pragma unroll
        for (int off = 1; off < 64; off <<= 1) {
            int x = __shfl_up(inc, off, 64);
            if (lane >= off) inc += x;
        }
        if (idx < nchunks) prefT[b * ncp + idx] = carry + inc - v;
        carry += __shfl(inc, 63, 64);
    }
    if (lane == 0) btot[b] = carry;
}

// ---------------- K3: partition (deterministic slots, no global atomics) ----------------
__global__ __launch_bounds__(256)
void partition_kernel(const int* __restrict__ src, const int* __restrict__ dst,
                      const int* __restrict__ histC, const int* __restrict__ prefT,
                      const int* __restrict__ btot, int* __restrict__ gbase,
                      unsigned* __restrict__ pairs, int E, int ncp)
{
    __shared__ int lbase[NBUCK];
    __shared__ int lcur[NBUCK];
    __shared__ int rb2[NBUCK];
    __shared__ int base_s[NBUCK];
    __shared__ int ssum[256];
    __shared__ unsigned sp[CHUNK];   // 8 KB
    __shared__ ushort  sb[CHUNK];    // 4 KB
    const int t = threadIdx.x, blk = blockIdx.x;

    // scan this chunk's hist -> lbase/lcur
    int4 cv = *(const int4*)&histC[blk * NBUCK + 4 * t];
    int tsum = cv.x + cv.y + cv.z + cv.w;
    ssum[t] = tsum;
    __syncthreads();
    for (int off = 1; off < 256; off <<= 1) {
        int x = (t >= off) ? ssum[t - off] : 0;
        __syncthreads();
        ssum[t] += x;
        __syncthreads();
    }
    int texcl = ssum[t] - tsum;
    lbase[4 * t]     = texcl;
    lbase[4 * t + 1] = texcl + cv.x;
    lbase[4 * t + 2] = texcl + cv.x + cv.y;
    lbase[4 * t + 3] = texcl + cv.x + cv.y + cv.z;
    lcur[4 * t]     = lbase[4 * t];
    lcur[4 * t + 1] = lbase[4 * t + 1];
    lcur[4 * t + 2] = lbase[4 * t + 2];
    lcur[4 * t + 3] = lbase[4 * t + 3];
    __syncthreads();

    // scan bucket totals -> base_s
    int4 bt = *(const int4*)&btot[4 * t];
    int bsum = bt.x + bt.y + bt.z + bt.w;
    ssum[t] = bsum;
    __syncthreads();
    for (int off = 1; off < 256; off <<= 1) {
        int x = (t >= off) ? ssum[t - off] : 0;
        __syncthreads();
        ssum[t] += x;
        __syncthreads();
    }
    int bexcl = ssum[t] - bsum;
    base_s[4 * t]     = bexcl;
    base_s[4 * t + 1] = bexcl + bt.x;
    base_s[4 * t + 2] = bexcl + bt.x + bt.y;
    base_s[4 * t + 3] = bexcl + bt.x + bt.y + bt.z;
    if (blk == 0) {
        *(int4*)&gbase[4 * t] = *(int4*)&base_s[4 * t];
        if (t == 255) gbase[NBUCK] = ssum[255];
    }
    __syncthreads();
    for (int i = t; i < NBUCK; i += 256)
        rb2[i] = base_s[i] + prefT[i * ncp + blk];
    __syncthreads();

    const int cb = blk * CHUNK, ce = min(cb + CHUNK, E);
    for (int e = cb + t; e < ce; e += 256) {
        int d = dst[e];
        int b = d >> BSH;
        unsigned packed = ((unsigned)src[e] << BSH) | (unsigned)(d & (BNODES - 1));
        int p = atomicAdd(&lcur[b], 1);
        sp[p] = packed;
        sb[p] = (ushort)b;
    }
    __syncthreads();
    const int cnt = ce - cb;
    for (int i = t; i < cnt; i += 256) {
        int b = sb[i];
        pairs[rb2[b] + (i - lbase[b])] = sp[i];
    }
}

// ---------------- K4: per-bucket CSR finalize ----------------
__global__ __launch_bounds__(256)
void bucket_csr(const unsigned* __restrict__ pairs, const int* __restrict__ base,
                int* __restrict__ row_start, float* __restrict__ dinv,
                unsigned* __restrict__ csr, int N, int E)
{
    __shared__ int deg[BNODES];
    __shared__ int s[BNODES];
    __shared__ int cur[BNODES];
    const int b = blockIdx.x, t = threadIdx.x;
    if (t < BNODES) deg[t] = 0;
    __syncthreads();
    const int rb = base[b], re = base[b + 1];
    for (int e = rb + t; e < re; e += 256)
        atomicAdd(&deg[pairs[e] & (BNODES - 1)], 1);
    __syncthreads();
    int v = (t < BNODES) ? deg[t] : 0;
    if (t < BNODES) s[t] = v;
    __syncthreads();
    for (int off = 1; off < BNODES; off <<= 1) {
        int x = (t >= off && t < BNODES) ? s[t - off] : 0;
        __syncthreads();
        if (t < BNODES) s[t] += x;
        __syncthreads();
    }
    const int n0 = b << BSH;
    if (t < BNODES) {
        int excl = s[t] - v;
        cur[t] = excl;
        if (n0 + t < N) {
            row_start[n0 + t] = rb + excl;
            dinv[n0 + t] = rsqrtf((float)v + 1.0f);
        }
    }
    if (b == gridDim.x - 1 && t == 0) row_start[N] = E;
    __syncthreads();
    for (int e = rb + t; e < re; e += 256) {
        unsigned p = pairs[e];
        int l = p & (BNODES - 1);
        int slot = atomicAdd(&cur[l], 1);
        csr[rb + slot] = p >> BSH;
    }
}

// ---------------- K5: fused pipelined GEMM: z' = (relu(x@W1^T+b1) @ W2^T) * dinv ----------------
//  * LDS = 32768 B declared: A0|B0|A1|B1 k-tiles (4 x [128][32] bf16 = 4x8KB, double-buffered),
//    fully aliased by unpadded swizzled Ht[128][128].
//  * B (W1, bf16) staged via global_load_lds dwordx4; w1b pre-swizzled in global, LDS linear,
//    ds_read applies the same XOR.  A reg-staged with the same chunk XOR at ds_write.
//  * Ht: stride 128, byte-XOR swizzle ((row&7)<<4) => conflict-free b128 frag reads.
//    [R2 PMC: SQ_LDS_BANK_CONFLICT 3.08M -> 200K confirms swizzles work.]
//  * Phase B: no LDS staging/barriers in k-loop; W2 frags direct from global (L2-hot).
//  * NO min-waves cap: __launch_bounds__(256,4) in R2 forced VGPR=64 -> massive scratch spill
//    (WRITE_SIZE 25->113 MB, dur 105us). Allocator must keep acc/acc2/prefetch in regs.
__global__ __launch_bounds__(256)
void gemm_fused(const float* __restrict__ X, const ushort* __restrict__ W1b,
                const ushort* __restrict__ W2b, const float* __restrict__ b1,
                const float* __restrict__ dinv, ushort* __restrict__ Zq, int M)
{
    __shared__ ushort smem[16384];          // 32768 B
    ushort* Ht = smem;                      // [128][128] bf16, swizzled, aliases all 4 k-tile bufs
    const int tid  = threadIdx.x;
    const int wave = tid >> 6, lane = tid & 63;
    const int wm = (wave & 1) * 64, wn = (wave >> 1) * 64;
    const int lr = lane & 15, lq = lane >> 4;
    const int m0 = blockIdx.x * 128;

    const int arow = tid >> 2;              // staging row (+64 for second)
    const int aq   = tid & 3;               // 16B chunk within the 64B k-slice

    float4 ar[2][2];
    auto loadX = [&](int k0) {
#pragma unroll
        for (int it = 0; it < 2; it++) {
            int row = arow + it * 64;
            ar[it][0] = make_float4(0.f, 0.f, 0.f, 0.f);
            ar[it][1] = make_float4(0.f, 0.f, 0.f, 0.f);
            if (m0 + row < M) {
                const float* p = &X[(long)(m0 + row) * F_IN + k0 + aq * 8];
                ar[it][0] = *(const float4*)p;
                ar[it][1] = *(const float4*)(p + 4);
            }
        }
    };
    auto writeA = [&](ushort* As) {
#pragma unroll
        for (int it = 0; it < 2; it++) {
            int row = arow + it * 64;
            ushort u[8] = { f2bf(ar[it][0].x), f2bf(ar[it][0].y), f2bf(ar[it][0].z), f2bf(ar[it][0].w),
                            f2bf(ar[it][1].x), f2bf(ar[it][1].y), f2bf(ar[it][1].z), f2bf(ar[it][1].w) };
            *(uint4*)&As[row * 32 + ((aq ^ ((row >> 1) & 3)) << 3)] = *(uint4*)u;
        }
    };
    auto stageB = [&](int k0, ushort* Bs) {
#pragma unroll
        for (int it = 0; it < 2; it++) {
            int r0 = wave * 32 + it * 16;                        // wave-uniform LDS dest
            const ushort* g = &W1b[(long)(r0 + (lane >> 2)) * F_IN + k0 + (lane & 3) * 8];
            gload_lds16(g, &Bs[r0 * 32]);
        }
    };

    // ---- phase A: acc = x @ W1^T (K=256) ----
    f32x4 acc[4][4] = {};
    loadX(0);
    stageB(0, smem + 4096);
    writeA(smem);
    __syncthreads();
    for (int k0 = 0; k0 < F_IN; k0 += 32) {
        const int cur = (k0 >> 5) & 1;
        ushort* As = smem + cur * 8192;
        ushort* Bs = As + 4096;
        const bool more = (k0 + 32 < F_IN);
        if (more) {
            stageB(k0 + 32, smem + (cur ^ 1) * 8192 + 4096);    // async DMA into alt buf
            loadX(k0 + 32);                                     // reg prefetch
        }
        bf16x8 af[4], bfr[4];
#pragma unroll
        for (int t4 = 0; t4 < 4; t4++) {
            int ra = wm + t4 * 16 + lr;
            int rb = wn + t4 * 16 + lr;
            af[t4]  = *(bf16x8*)&As[ra * 32 + ((lq ^ ((ra >> 1) & 3)) << 3)];
            bfr[t4] = *(bf16x8*)&Bs[rb * 32 + ((lq ^ ((rb >> 1) & 3)) << 3)];
        }
#pragma unroll
        for (int i = 0; i < 4; i++)
#pragma unroll
            for (int j = 0; j < 4; j++)
                acc[i][j] = __builtin_amdgcn_mfma_f32_16x16x32_bf16(af[i], bfr[j], acc[i][j], 0, 0, 0);
        if (more) writeA(smem + (cur ^ 1) * 8192);              // cvt+ds_write into alt buf
        __syncthreads();
    }

    // prefetch W2 frags for k0=0 (latency hidden under epilogue A)
    uint4 wb[2][4];
#pragma unroll
    for (int t4 = 0; t4 < 4; t4++)
        wb[0][t4] = *(const uint4*)&W2b[(long)(wn + t4 * 16 + lr) * CCH + lq * 8];

    // ---- epilogue A: h = relu(acc + b1) -> Ht (swizzled) ----
    {
        float bv[4];
#pragma unroll
        for (int j = 0; j < 4; j++) bv[j] = b1[wn + j * 16 + lr];
#pragma unroll
        for (int i = 0; i < 4; i++)
#pragma unroll
            for (int r = 0; r < 4; r++) {
                int row = wm + i * 16 + lq * 4 + r;
                int rx  = (row & 7) << 3;
#pragma unroll
                for (int j = 0; j < 4; j++)
                    Ht[row * 128 + ((wn + j * 16 + lr) ^ rx)] = f2bf(fmaxf(acc[i][j][r] + bv[j], 0.f));
            }
    }
    __syncthreads();

    // ---- phase B: acc2 = h @ W2^T (K=128), barrier-free: A from Ht, B direct from global ----
    f32x4 acc2[4][4] = {};
#pragma unroll
    for (int kk = 0; kk < 4; kk++) {
        const int k0 = kk * 32;
        if (kk < 3) {
#pragma unroll
            for (int t4 = 0; t4 < 4; t4++)
                wb[(kk + 1) & 1][t4] =
                    *(const uint4*)&W2b[(long)(wn + t4 * 16 + lr) * CCH + k0 + 32 + lq * 8];
        }
        bf16x8 af[4];
#pragma unroll
        for (int t4 = 0; t4 < 4; t4++) {
            int ra = wm + t4 * 16 + lr;
            af[t4] = *(bf16x8*)&Ht[ra * 128 + ((k0 + lq * 8) ^ ((ra & 7) << 3))];
        }
#pragma unroll
        for (int i = 0; i < 4; i++)
#pragma unroll
            for (int j = 0; j < 4; j++)
                acc2[i][j] = __builtin_amdgcn_mfma_f32_16x16x32_bf16(af[i], *(bf16x8*)&wb[kk & 1][j],
                                                                     acc2[i][j], 0, 0, 0);
    }
    __syncthreads();   // all Ht frag reads done before overwrite

    // ---- epilogue B: z' = acc2 * dinv -> Ht (swizzled) -> coalesced store ----
#pragma unroll
    for (int i = 0; i < 4; i++)
#pragma unroll
        for (int r = 0; r < 4; r++) {
            int row = wm + i * 16 + lq * 4 + r;
            int rx  = (row & 7) << 3;
            float di = (m0 + row < M) ? dinv[m0 + row] : 0.f;
#pragma unroll
            for (int j = 0; j < 4; j++)
                Ht[row * 128 + ((wn + j * 16 + lr) ^ rx)] = f2bf(acc2[i][j][r] * di);
        }
    __syncthreads();
    {
        int colq = tid & 15, row0 = tid >> 4;
#pragma unroll
        for (int i = 0; i < 8; i++) {
            int row = row0 + i * 16;
            if (m0 + row < M)
                *(uint4*)&Zq[(long)(m0 + row) * CCH + colq * 8] =
                    *(uint4*)&Ht[row * 128 + ((colq * 8) ^ ((row & 7) << 3))];
        }
    }
}

// ---------------- K6: gather ----------------
__global__ __launch_bounds__(256)
void gather_nodes(const unsigned* __restrict__ zq, const unsigned* __restrict__ csr,
                  const int* __restrict__ row_start, const float* __restrict__ dinv,
                  const float* __restrict__ b2, float* __restrict__ out, int N)
{
    const int node = blockIdx.x * 4 + (threadIdx.x >> 6);
    const int lane = threadIdx.x & 63;
    if (node >= N) return;

    float2 zs = bf2f2(zq[(long)node * 64 + lane]);
    float acc0 = zs.x, acc1 = zs.y;

    const int rs = row_start[node];
    const int re = row_start[node + 1];
    int j = rs;
    for (; j + 8 <= re; j += 8) {
        unsigned sI[8], zv[8];
#pragma unroll
        for (int q = 0; q < 8; q++) sI[q] = csr[j + q];
#pragma unroll
        for (int q = 0; q < 8; q++) zv[q] = zq[(long)sI[q] * 64 + lane];
#pragma unroll
        for (int q = 0; q < 8; q++) { float2 f = bf2f2(zv[q]); acc0 += f.x; acc1 += f.y; }
    }
    for (; j < re; j++) {
        float2 f = bf2f2(zq[(long)csr[j] * 64 + lane]);
        acc0 += f.x; acc1 += f.y;
    }

    float di = dinv[node];
    float2 o;
    o.x = b2[lane * 2 + 0] + di * acc0;
    o.y = b2[lane * 2 + 1] + di * acc1;
    *(float2*)&out[(long)node * CCH + lane * 2] = o;
}

extern "C" void kernel_launch(void* const* d_in, const int* in_sizes, int n_in,
                              void* d_out, int out_size, void* d_ws, size_t ws_size,
                              hipStream_t stream)
{
    const float* x  = (const float*)d_in[0];
    const int*   ei = (const int*)d_in[1];
    const float* W1 = (const float*)d_in[2];
    const float* b1 = (const float*)d_in[3];
    const float* W2 = (const float*)d_in[4];
    const float* b2 = (const float*)d_in[5];
    float* out = (float*)d_out;

    const int N = in_sizes[0] / F_IN;
    const int E = in_sizes[1] / 2;
    const int* src = ei;
    const int* dst = ei + E;

    const int nchunks = (E + CHUNK - 1) / CHUNK;        // 782
    const int ncp     = (nchunks + 63) & ~63;           // 832
    const int nbuck   = (N + BNODES - 1) / BNODES;      // 782
    const int ngrid   = (N + 127) / 128;
    const int ncvt    = (CCH * F_IN + CCH * CCH + 255) / 256;

    char* ws = (char*)d_ws;
    ushort* zq    = (ushort*)ws;   ws += (size_t)N * CCH * 2;
    ushort* w1b   = (ushort*)ws;   ws += (size_t)CCH * F_IN * 2;
    ushort* w2b   = (ushort*)ws;   ws += (size_t)CCH * CCH * 2;
    unsigned* prs = (unsigned*)ws; ws += (size_t)E * 4;
    unsigned* csr = (unsigned*)ws; ws += (size_t)E * 4;
    int* rstart   = (int*)ws;      ws += ((size_t)N + 1) * 4;
    float* dinv   = (float*)ws;    ws += (size_t)N * 4;
    int* histC    = (int*)ws;      ws += (size_t)nchunks * NBUCK * 4;
    int* histT    = (int*)ws;      ws += (size_t)NBUCK * ncp * 4;
    int* prefT    = (int*)ws;      ws += (size_t)NBUCK * ncp * 4;
    int* btot     = (int*)ws;      ws += NBUCK * 4;
    int* gbase    = (int*)ws;      ws += (NBUCK + 1) * 4;

    // build
    hist_cvt<<<nchunks + ncvt, 256, 0, stream>>>(dst, histC, histT, E, nchunks, ncp, W1, W2, w1b, w2b);
    scan_buckets<<<NBUCK / 4, 256, 0, stream>>>(histT, prefT, btot, nchunks, ncp);
    partition_kernel<<<nchunks, 256, 0, stream>>>(src, dst, histC, prefT, btot, gbase, prs, E, ncp);
    bucket_csr<<<nbuck, 256, 0, stream>>>(prs, gbase, rstart, dinv, csr, N, E);

    // fused GEMMs: z' = (relu(x@W1^T + b1) @ W2^T) * dinv   [bf16]
    gemm_fused<<<ngrid, 256, 0, stream>>>(x, w1b, w2b, b1, dinv, zq, N);

    // aggregate
    gather_nodes<<<(N + 3) / 4, 256, 0, stream>>>((const unsigned*)zq, csr, rstart, dinv, b2, out, N);
}

// Round 4
// 318.839 us; speedup vs baseline: 1.1443x; 1.0133x over previous
//
#include <hip/hip_runtime.h>

typedef unsigned short ushort;
typedef __bf16 bf16x8 __attribute__((ext_vector_type(8)));
typedef float f32x4 __attribute__((ext_vector_type(4)));

#define F_IN 256
#define CCH  128
#define BSH  7
#define BNODES 128
#define NBUCK 1024
#define CHUNK 2048

// ---------------- helpers ----------------
__device__ __forceinline__ ushort f2bf(float f) {
    union { float f; unsigned i; } u; u.f = f;
    unsigned r = u.i + 0x7fffu + ((u.i >> 16) & 1u);   // RNE
    return (ushort)(r >> 16);
}
__device__ __forceinline__ float2 bf2f2(unsigned u) {
    union { unsigned i; float f; } lo, hi;
    lo.i = u << 16;
    hi.i = u & 0xffff0000u;
    return make_float2(lo.f, hi.f);
}
__device__ __forceinline__ void gload_lds16(const void* g, void* l) {
    __builtin_amdgcn_global_load_lds((const __attribute__((address_space(1))) unsigned*)g,
                                     (__attribute__((address_space(3))) unsigned*)l, 16, 0, 0);
}

// ---------------- K1: per-chunk histogram (dual layout) + weight cvt ----------------
// w1b is written PRE-SWIZZLED: within each 32-col k-tile, 8-elem chunk c -> c ^ ((row>>1)&3).
__global__ __launch_bounds__(256)
void hist_cvt(const int* __restrict__ dst, int* __restrict__ histC, int* __restrict__ histT,
              int E, int nchunks, int ncp,
              const float* __restrict__ W1, const float* __restrict__ W2,
              ushort* __restrict__ w1b, ushort* __restrict__ w2b)
{
    const int blk = blockIdx.x, t = threadIdx.x;
    if (blk >= nchunks) {
        int i = (blk - nchunks) * 256 + t;
        if (i < CCH * F_IN) {
            int c  = i & 31;
            int cs = c ^ (((i >> 9) & 3) << 3);        // (row>>1)&3, row = i>>8
            w1b[(i & ~31) | cs] = f2bf(W1[i]);
        } else {
            int j = i - CCH * F_IN;
            if (j < CCH * CCH) w2b[j] = f2bf(W2[j]);
        }
        return;
    }
    __shared__ int h[NBUCK];
    for (int i = t; i < NBUCK; i += 256) h[i] = 0;
    __syncthreads();
    int cb = blk * CHUNK, ce = min(cb + CHUNK, E);
    for (int e = cb + t; e < ce; e += 256)
        atomicAdd(&h[dst[e] >> BSH], 1);
    __syncthreads();
    for (int i = t; i < NBUCK; i += 256) {
        int v = h[i];
        histC[blk * NBUCK + i] = v;     // chunk-major (partition)
        histT[i * ncp + blk]   = v;     // bucket-major (scan)
    }
}

// ---------------- K2: per-bucket cross-chunk prefix (one wave per bucket) ----------------
__global__ __launch_bounds__(256)
void scan_buckets(const int* __restrict__ histT, int* __restrict__ prefT,
                  int* __restrict__ btot, int nchunks, int ncp)
{
    const int b = blockIdx.x * 4 + (threadIdx.x >> 6);
    const int lane = threadIdx.x & 63;
    int carry = 0;
    for (int c = 0; c < nchunks; c += 64) {
        int idx = c + lane;
        int v = (idx < nchunks) ? histT[b * ncp + idx] : 0;
        int inc = v;
#pragma unroll
        for (int off = 1; off < 64; off <<= 1) {
            int x = __shfl_up(inc, off, 64);
            if (lane >= off) inc += x;
        }
        if (idx < nchunks) prefT[b * ncp + idx] = carry + inc - v;
        carry += __shfl(inc, 63, 64);
    }
    if (lane == 0) btot[b] = carry;
}

// ---------------- device body: partition (deterministic slots) ----------------
// LDS carve from smem4 (8192 u32 = 32 KB): lbase|lcur|rb2|base_s (4x1024) ssum(256) sp(2048) sb(1024)
__device__ __forceinline__ void partition_body(unsigned* smem4,
    const int* __restrict__ src, const int* __restrict__ dst,
    const int* __restrict__ histC, const int* __restrict__ prefT,
    const int* __restrict__ btot, int* __restrict__ gbase,
    unsigned* __restrict__ pairs, int E, int ncp, int blk)
{
    int* lbase  = (int*)smem4;
    int* lcur   = lbase + NBUCK;
    int* rb2    = lcur + NBUCK;
    int* base_s = rb2 + NBUCK;
    int* ssum   = base_s + NBUCK;          // 256
    unsigned* sp = (unsigned*)(ssum + 256); // 2048
    ushort* sb  = (ushort*)(sp + CHUNK);    // 2048 ushort
    const int t = threadIdx.x;

    int4 cv = *(const int4*)&histC[blk * NBUCK + 4 * t];
    int tsum = cv.x + cv.y + cv.z + cv.w;
    ssum[t] = tsum;
    __syncthreads();
    for (int off = 1; off < 256; off <<= 1) {
        int x = (t >= off) ? ssum[t - off] : 0;
        __syncthreads();
        ssum[t] += x;
        __syncthreads();
    }
    int texcl = ssum[t] - tsum;
    lbase[4 * t]     = texcl;
    lbase[4 * t + 1] = texcl + cv.x;
    lbase[4 * t + 2] = texcl + cv.x + cv.y;
    lbase[4 * t + 3] = texcl + cv.x + cv.y + cv.z;
    lcur[4 * t]     = lbase[4 * t];
    lcur[4 * t + 1] = lbase[4 * t + 1];
    lcur[4 * t + 2] = lbase[4 * t + 2];
    lcur[4 * t + 3] = lbase[4 * t + 3];
    __syncthreads();

    int4 bt = *(const int4*)&btot[4 * t];
    int bsum = bt.x + bt.y + bt.z + bt.w;
    ssum[t] = bsum;
    __syncthreads();
    for (int off = 1; off < 256; off <<= 1) {
        int x = (t >= off) ? ssum[t - off] : 0;
        __syncthreads();
        ssum[t] += x;
        __syncthreads();
    }
    int bexcl = ssum[t] - bsum;
    base_s[4 * t]     = bexcl;
    base_s[4 * t + 1] = bexcl + bt.x;
    base_s[4 * t + 2] = bexcl + bt.x + bt.y;
    base_s[4 * t + 3] = bexcl + bt.x + bt.y + bt.z;
    if (blk == 0) {
        *(int4*)&gbase[4 * t] = *(int4*)&base_s[4 * t];
        if (t == 255) gbase[NBUCK] = ssum[255];
    }
    __syncthreads();
    for (int i = t; i < NBUCK; i += 256)
        rb2[i] = base_s[i] + prefT[i * ncp + blk];
    __syncthreads();

    const int cb = blk * CHUNK, ce = min(cb + CHUNK, E);
    for (int e = cb + t; e < ce; e += 256) {
        int d = dst[e];
        int b = d >> BSH;
        unsigned packed = ((unsigned)src[e] << BSH) | (unsigned)(d & (BNODES - 1));
        int p = atomicAdd(&lcur[b], 1);
        sp[p] = packed;
        sb[p] = (ushort)b;
    }
    __syncthreads();
    const int cnt = ce - cb;
    for (int i = t; i < cnt; i += 256) {
        int b = sb[i];
        pairs[rb2[b] + (i - lbase[b])] = sp[i];
    }
}

// ---------------- device body: per-bucket CSR finalize ----------------
__device__ __forceinline__ void csr_body(unsigned* smem4,
    const unsigned* __restrict__ pairs, const int* __restrict__ base,
    int* __restrict__ row_start, float* __restrict__ dinv,
    unsigned* __restrict__ csr, int N, int E, int b, int lastb)
{
    int* deg = (int*)smem4;
    int* s   = deg + BNODES;
    int* cur = s + BNODES;
    const int t = threadIdx.x;
    if (t < BNODES) deg[t] = 0;
    __syncthreads();
    const int rb = base[b], re = base[b + 1];
    for (int e = rb + t; e < re; e += 256)
        atomicAdd(&deg[pairs[e] & (BNODES - 1)], 1);
    __syncthreads();
    int v = (t < BNODES) ? deg[t] : 0;
    if (t < BNODES) s[t] = v;
    __syncthreads();
    for (int off = 1; off < BNODES; off <<= 1) {
        int x = (t >= off && t < BNODES) ? s[t - off] : 0;
        __syncthreads();
        if (t < BNODES) s[t] += x;
        __syncthreads();
    }
    const int n0 = b << BSH;
    if (t < BNODES) {
        int excl = s[t] - v;
        cur[t] = excl;
        if (n0 + t < N) {
            row_start[n0 + t] = rb + excl;
            dinv[n0 + t] = rsqrtf((float)v + 1.0f);
        }
    }
    if (b == lastb && t == 0) row_start[N] = E;
    __syncthreads();
    for (int e = rb + t; e < re; e += 256) {
        unsigned p = pairs[e];
        int l = p & (BNODES - 1);
        int slot = atomicAdd(&cur[l], 1);
        csr[rb + slot] = p >> BSH;
    }
}

// ---------------- device body: fused GEMM  zq = relu(x@W1^T+b1) @ W2^T  (NO dinv) ----------------
// [R3 PMC: bank conflicts 3.08M->200K; VGPR uncapped avoids R2 spill (WRITE 113MB->25MB).]
// dinv factor moved to gather so gemm has no dependency on the CSR build chain -> fused-grid overlap.
__device__ __forceinline__ void gemm_body(unsigned* smem4,
    const float* __restrict__ X, const ushort* __restrict__ W1b,
    const ushort* __restrict__ W2b, const float* __restrict__ b1,
    ushort* __restrict__ Zq, int M, int m0)
{
    ushort* smem = (ushort*)smem4;          // 32768 B: dbuf k-tiles, aliased by Ht[128][128]
    ushort* Ht = smem;
    const int tid  = threadIdx.x;
    const int wave = tid >> 6, lane = tid & 63;
    const int wm = (wave & 1) * 64, wn = (wave >> 1) * 64;
    const int lr = lane & 15, lq = lane >> 4;

    const int arow = tid >> 2;
    const int aq   = tid & 3;

    float4 ar[2][2];
    auto loadX = [&](int k0) {
#pragma unroll
        for (int it = 0; it < 2; it++) {
            int row = arow + it * 64;
            ar[it][0] = make_float4(0.f, 0.f, 0.f, 0.f);
            ar[it][1] = make_float4(0.f, 0.f, 0.f, 0.f);
            if (m0 + row < M) {
                const float* p = &X[(long)(m0 + row) * F_IN + k0 + aq * 8];
                ar[it][0] = *(const float4*)p;
                ar[it][1] = *(const float4*)(p + 4);
            }
        }
    };
    auto writeA = [&](ushort* As) {
#pragma unroll
        for (int it = 0; it < 2; it++) {
            int row = arow + it * 64;
            ushort u[8] = { f2bf(ar[it][0].x), f2bf(ar[it][0].y), f2bf(ar[it][0].z), f2bf(ar[it][0].w),
                            f2bf(ar[it][1].x), f2bf(ar[it][1].y), f2bf(ar[it][1].z), f2bf(ar[it][1].w) };
            *(uint4*)&As[row * 32 + ((aq ^ ((row >> 1) & 3)) << 3)] = *(uint4*)u;
        }
    };
    auto stageB = [&](int k0, ushort* Bs) {
#pragma unroll
        for (int it = 0; it < 2; it++) {
            int r0 = wave * 32 + it * 16;                        // wave-uniform LDS dest
            const ushort* g = &W1b[(long)(r0 + (lane >> 2)) * F_IN + k0 + (lane & 3) * 8];
            gload_lds16(g, &Bs[r0 * 32]);
        }
    };

    // ---- phase A: acc = x @ W1^T (K=256) ----
    f32x4 acc[4][4] = {};
    loadX(0);
    stageB(0, smem + 4096);
    writeA(smem);
    __syncthreads();
    for (int k0 = 0; k0 < F_IN; k0 += 32) {
        const int cur = (k0 >> 5) & 1;
        ushort* As = smem + cur * 8192;
        ushort* Bs = As + 4096;
        const bool more = (k0 + 32 < F_IN);
        if (more) {
            stageB(k0 + 32, smem + (cur ^ 1) * 8192 + 4096);
            loadX(k0 + 32);
        }
        bf16x8 af[4], bfr[4];
#pragma unroll
        for (int t4 = 0; t4 < 4; t4++) {
            int ra = wm + t4 * 16 + lr;
            int rb = wn + t4 * 16 + lr;
            af[t4]  = *(bf16x8*)&As[ra * 32 + ((lq ^ ((ra >> 1) & 3)) << 3)];
            bfr[t4] = *(bf16x8*)&Bs[rb * 32 + ((lq ^ ((rb >> 1) & 3)) << 3)];
        }
#pragma unroll
        for (int i = 0; i < 4; i++)
#pragma unroll
            for (int j = 0; j < 4; j++)
                acc[i][j] = __builtin_amdgcn_mfma_f32_16x16x32_bf16(af[i], bfr[j], acc[i][j], 0, 0, 0);
        if (more) writeA(smem + (cur ^ 1) * 8192);
        __syncthreads();
    }

    // prefetch W2 frags for k0=0
    uint4 wb[2][4];
#pragma unroll
    for (int t4 = 0; t4 < 4; t4++)
        wb[0][t4] = *(const uint4*)&W2b[(long)(wn + t4 * 16 + lr) * CCH + lq * 8];

    // ---- epilogue A: h = relu(acc + b1) -> Ht (swizzled) ----
    {
        float bv[4];
#pragma unroll
        for (int j = 0; j < 4; j++) bv[j] = b1[wn + j * 16 + lr];
#pragma unroll
        for (int i = 0; i < 4; i++)
#pragma unroll
            for (int r = 0; r < 4; r++) {
                int row = wm + i * 16 + lq * 4 + r;
                int rx  = (row & 7) << 3;
#pragma unroll
                for (int j = 0; j < 4; j++)
                    Ht[row * 128 + ((wn + j * 16 + lr) ^ rx)] = f2bf(fmaxf(acc[i][j][r] + bv[j], 0.f));
            }
    }
    __syncthreads();

    // ---- phase B: acc2 = h @ W2^T (K=128), barrier-free ----
    f32x4 acc2[4][4] = {};
#pragma unroll
    for (int kk = 0; kk < 4; kk++) {
        const int k0 = kk * 32;
        if (kk < 3) {
#pragma unroll
            for (int t4 = 0; t4 < 4; t4++)
                wb[(kk + 1) & 1][t4] =
                    *(const uint4*)&W2b[(long)(wn + t4 * 16 + lr) * CCH + k0 + 32 + lq * 8];
        }
        bf16x8 af[4];
#pragma unroll
        for (int t4 = 0; t4 < 4; t4++) {
            int ra = wm + t4 * 16 + lr;
            af[t4] = *(bf16x8*)&Ht[ra * 128 + ((k0 + lq * 8) ^ ((ra & 7) << 3))];
        }
#pragma unroll
        for (int i = 0; i < 4; i++)
#pragma unroll
            for (int j = 0; j < 4; j++)
                acc2[i][j] = __builtin_amdgcn_mfma_f32_16x16x32_bf16(af[i], *(bf16x8*)&wb[kk & 1][j],
                                                                     acc2[i][j], 0, 0, 0);
    }
    __syncthreads();

    // ---- epilogue B: z -> Ht (swizzled) -> coalesced store (no dinv here) ----
#pragma unroll
    for (int i = 0; i < 4; i++)
#pragma unroll
        for (int r = 0; r < 4; r++) {
            int row = wm + i * 16 + lq * 4 + r;
            int rx  = (row & 7) << 3;
#pragma unroll
            for (int j = 0; j < 4; j++)
                Ht[row * 128 + ((wn + j * 16 + lr) ^ rx)] = f2bf(acc2[i][j][r]);
        }
    __syncthreads();
    {
        int colq = tid & 15, row0 = tid >> 4;
#pragma unroll
        for (int i = 0; i < 8; i++) {
            int row = row0 + i * 16;
            if (m0 + row < M)
                *(uint4*)&Zq[(long)(m0 + row) * CCH + colq * 8] =
                    *(uint4*)&Ht[row * 128 + ((colq * 8) ^ ((row & 7) << 3))];
        }
    }
}

// ---------------- U1: gemm half A (blocks first) ∪ partition ----------------
__global__ __launch_bounds__(256)
void u_part_gemm(const int* __restrict__ src, const int* __restrict__ dst,
                 const int* __restrict__ histC, const int* __restrict__ prefT,
                 const int* __restrict__ btot, int* __restrict__ gbase,
                 unsigned* __restrict__ pairs, int E, int ncp, int ngA,
                 const float* __restrict__ X, const ushort* __restrict__ W1b,
                 const ushort* __restrict__ W2b, const float* __restrict__ b1,
                 ushort* __restrict__ Zq, int M)
{
    __shared__ unsigned smem4[8192];    // 32 KB, carved per path
    if ((int)blockIdx.x < ngA)
        gemm_body(smem4, X, W1b, W2b, b1, Zq, M, blockIdx.x * 128);
    else
        partition_body(smem4, src, dst, histC, prefT, btot, gbase, pairs, E, ncp,
                       blockIdx.x - ngA);
}

// ---------------- U2: gemm half B (blocks first) ∪ bucket CSR ----------------
__global__ __launch_bounds__(256)
void u_csr_gemm(const unsigned* __restrict__ pairs, const int* __restrict__ base,
                int* __restrict__ row_start, float* __restrict__ dinv,
                unsigned* __restrict__ csr, int N, int E, int ngB, int ngA, int nbuck,
                const float* __restrict__ X, const ushort* __restrict__ W1b,
                const ushort* __restrict__ W2b, const float* __restrict__ b1,
                ushort* __restrict__ Zq, int M)
{
    __shared__ unsigned smem4[8192];
    if ((int)blockIdx.x < ngB)
        gemm_body(smem4, X, W1b, W2b, b1, Zq, M, (ngA + blockIdx.x) * 128);
    else
        csr_body(smem4, pairs, base, row_start, dinv, csr, N, E,
                 blockIdx.x - ngB, nbuck - 1);
}

// ---------------- K6: gather (dinv[src] applied here now) ----------------
__global__ __launch_bounds__(256)
void gather_nodes(const unsigned* __restrict__ zq, const unsigned* __restrict__ csr,
                  const int* __restrict__ row_start, const float* __restrict__ dinv,
                  const float* __restrict__ b2, float* __restrict__ out, int N)
{
    const int node = blockIdx.x * 4 + (threadIdx.x >> 6);
    const int lane = threadIdx.x & 63;
    if (node >= N) return;

    const float di = dinv[node];
    float2 zs = bf2f2(zq[(long)node * 64 + lane]);
    float acc0 = di * zs.x, acc1 = di * zs.y;      // self-loop: dinv[d]*z[d]

    const int rs = row_start[node];
    const int re = row_start[node + 1];
    int j = rs;
    for (; j + 8 <= re; j += 8) {
        unsigned sI[8], zv[8];
        float dv[8];
#pragma unroll
        for (int q = 0; q < 8; q++) sI[q] = csr[j + q];
#pragma unroll
        for (int q = 0; q < 8; q++) dv[q] = dinv[sI[q]];
#pragma unroll
        for (int q = 0; q < 8; q++) zv[q] = zq[(long)sI[q] * 64 + lane];
#pragma unroll
        for (int q = 0; q < 8; q++) { float2 f = bf2f2(zv[q]); acc0 += dv[q] * f.x; acc1 += dv[q] * f.y; }
    }
    for (; j < re; j++) {
        unsigned s = csr[j];
        float ds = dinv[s];
        float2 f = bf2f2(zq[(long)s * 64 + lane]);
        acc0 += ds * f.x; acc1 += ds * f.y;
    }

    float2 o;
    o.x = b2[lane * 2 + 0] + di * acc0;
    o.y = b2[lane * 2 + 1] + di * acc1;
    *(float2*)&out[(long)node * CCH + lane * 2] = o;
}

extern "C" void kernel_launch(void* const* d_in, const int* in_sizes, int n_in,
                              void* d_out, int out_size, void* d_ws, size_t ws_size,
                              hipStream_t stream)
{
    const float* x  = (const float*)d_in[0];
    const int*   ei = (const int*)d_in[1];
    const float* W1 = (const float*)d_in[2];
    const float* b1 = (const float*)d_in[3];
    const float* W2 = (const float*)d_in[4];
    const float* b2 = (const float*)d_in[5];
    float* out = (float*)d_out;

    const int N = in_sizes[0] / F_IN;
    const int E = in_sizes[1] / 2;
    const int* src = ei;
    const int* dst = ei + E;

    const int nchunks = (E + CHUNK - 1) / CHUNK;        // 782
    const int ncp     = (nchunks + 63) & ~63;           // 832
    const int nbuck   = (N + BNODES - 1) / BNODES;      // 782
    const int ngrid   = (N + 127) / 128;                // 782
    const int ngA     = (ngrid + 1) / 2;                // 391 (gemm half A)
    const int ngB     = ngrid - ngA;                    // 391 (gemm half B)
    const int ncvt    = (CCH * F_IN + CCH * CCH + 255) / 256;

    char* ws = (char*)d_ws;
    ushort* zq    = (ushort*)ws;   ws += (size_t)N * CCH * 2;
    ushort* w1b   = (ushort*)ws;   ws += (size_t)CCH * F_IN * 2;
    ushort* w2b   = (ushort*)ws;   ws += (size_t)CCH * CCH * 2;
    unsigned* prs = (unsigned*)ws; ws += (size_t)E * 4;
    unsigned* csr = (unsigned*)ws; ws += (size_t)E * 4;
    int* rstart   = (int*)ws;      ws += ((size_t)N + 1) * 4;
    float* dinv   = (float*)ws;    ws += (size_t)N * 4;
    int* histC    = (int*)ws;      ws += (size_t)nchunks * NBUCK * 4;
    int* histT    = (int*)ws;      ws += (size_t)NBUCK * ncp * 4;
    int* prefT    = (int*)ws;      ws += (size_t)NBUCK * ncp * 4;
    int* btot     = (int*)ws;      ws += NBUCK * 4;
    int* gbase    = (int*)ws;      ws += (NBUCK + 1) * 4;

    // K1: histogram + weight cvt
    hist_cvt<<<nchunks + ncvt, 256, 0, stream>>>(dst, histC, histT, E, nchunks, ncp, W1, W2, w1b, w2b);
    // K2: bucket scan
    scan_buckets<<<NBUCK / 4, 256, 0, stream>>>(histT, prefT, btot, nchunks, ncp);
    // U1: partition ∪ gemm-half-A (independent chains multiplexed in one grid)
    u_part_gemm<<<ngA + nchunks, 256, 0, stream>>>(src, dst, histC, prefT, btot, gbase, prs, E, ncp,
                                                   ngA, x, w1b, w2b, b1, zq, N);
    // U2: bucket-CSR ∪ gemm-half-B
    u_csr_gemm<<<ngB + nbuck, 256, 0, stream>>>(prs, gbase, rstart, dinv, csr, N, E,
                                                ngB, ngA, nbuck, x, w1b, w2b, b1, zq, N);
    // K6: aggregate (applies dinv[src] * dinv[dst] here)
    gather_nodes<<<(N + 3) / 4, 256, 0, stream>>>((const unsigned*)zq, csr, rstart, dinv, b2, out, N);
}